// Round 5
// baseline (4393.328 us; speedup 1.0000x reference)
//
#include <hip/hip_runtime.h>
#include <stdint.h>

#define NN 2048
#define TT 365
#define DD 16
#define HH 64
#define NBLK 128      // 16 rows per block, 1 block/CU (LDS-bound)
#define NTHR 1024     // 16 waves
#define SMEM_BYTES 152192
#define QSLOT_U32 65536          // 64 cols x 2048 nodes bf16 = 256 KB per ring slot
#define SENT32 0xFFFFFFFFu       // bf16 NaN pair: unreachable for tanh output

typedef __attribute__((ext_vector_type(8))) short bf16x8;
typedef __attribute__((ext_vector_type(4))) float f32x4;
typedef __attribute__((ext_vector_type(4))) unsigned int u32x4;

__device__ __forceinline__ unsigned short f2bf(float f) {
  union { float f; uint32_t u; } z; z.f = f;
  uint32_t r = z.u + 0x7fffu + ((z.u >> 16) & 1u);
  return (unsigned short)(r >> 16);
}
__device__ __forceinline__ float bf2f(unsigned short b) {
  union { uint32_t u; float f; } z; z.u = (uint32_t)b << 16; return z.f;
}
__device__ __forceinline__ float sigmoid_(float x) { return 1.f / (1.f + __expf(-x)); }
__device__ __forceinline__ float tanh_(float x) {
  float ax = fabsf(x);
  float e = __expf(-2.f * ax);
  float r = (1.f - e) / (1.f + e);
  return x < 0.f ? -r : r;
}
__device__ __forceinline__ bf16x8 asbf(u32x4 v) { return __builtin_bit_cast(bf16x8, v); }

// R18: serial-chain trim. (a) Gate columns INTERLEAVED in the staged weight
// matrix (phys col p = logical col p>>2, gate p&3) so the 4 gates of a cell
// live in 4 ADJACENT LANES of one wave -> gate exchange is 16 intra-wave
// shfls; sh_g LDS round-trip and barriers B1/B2 deleted (2 barriers/step
// remain). (b) q-loads issued at loop TOP, overlapped by gates-GEMM +
// activations; busy retry (no s_sleep -> no 128-cy wake quantization, keeps
// clocks up). (c) update computed 4x-redundantly per 4-lane group (free);
// f32 h kept in shf32 LDS for bit-identical output projection.
// Sync = R17 flag-free tag-in-data (sentinel 0xFF ring, write-once).
__global__ __launch_bounds__(NTHR) __attribute__((amdgpu_waves_per_eu(4, 4)))
void rgcn_persist(
    const float* __restrict__ X, const float* __restrict__ Af,
    const float* __restrict__ Wih, const float* __restrict__ Whh,
    const float* __restrict__ Bias, const float* __restrict__ Wq,
    const float* __restrict__ Bq, const float* __restrict__ Wd,
    const float* __restrict__ Bd, float* __restrict__ Out,
    uint32_t* qRing, uint32_t* flags, int rdepth, int ringfull)
{
  extern __shared__ __align__(16) char smem[];
  unsigned short* afrag = (unsigned short*)smem;                 // [64kc][64ln][8] 65536
  unsigned short* whxT  = (unsigned short*)(smem + 65536);       // [256n][104k]    53248
  unsigned short* wqT   = (unsigned short*)(smem + 118784);      // [64n][72k]       9216
  f32x4*          sh_part = (f32x4*)(smem + 128000);             // [16][65] f32x4  16640
  float*          shf32 = (float*)(smem + 144640);               // [16][65] f32 h   4160
  unsigned short* sh_hx = (unsigned short*)(smem + 148800);      // [16][104] bf16   3328
  unsigned int*   cnt   = (unsigned int*)(smem + 152128);        // fallback arrival ctr

  const int tid = threadIdx.x;
  const int w = tid >> 6;        // wave 0..15
  const int c = tid & 63;        // lane
  const int base = blockIdx.x * 16;
  const int m = c & 15, quad = c >> 4;
  const int nt = w & 3, kh = w >> 2;                       // phase B tile coords

  // ---- one-time staging ----
  for (int i = tid; i < 256 * 104; i += NTHR) {            // [WhhT|WihT|0], gate-interleaved
    int n = i / 104, k = i - n * 104;                      // n = PHYSICAL col
    int src = (n & 3) * 64 + (n >> 2);                     // logical source col
    float v = (k < 64) ? Whh[k * 256 + src] : (k < 80) ? Wih[(k - 64) * 256 + src] : 0.f;
    whxT[i] = f2bf(v);
  }
  for (int i = tid; i < 64 * 72; i += NTHR) {              // WqT (pad k 64..71 = 0)
    int n = i / 72, k = i - n * 72;
    wqT[i] = (k < 64) ? f2bf(Wq[k * 64 + n]) : (unsigned short)0;
  }
  for (int i = tid; i < 16 * NN; i += NTHR) {              // A -> MFMA A-frag layout
    int r = i >> 11, k = i & (NN - 1);
    afrag[(k >> 5) * 512 + (((k >> 3) & 3) * 16 + r) * 8 + (k & 7)] =
        f2bf(Af[(size_t)(base + r) * NN + k]);
  }
  for (int i = tid; i < 16 * 104; i += NTHR) sh_hx[i] = 0; // h=0, x below, pad=0
  __syncthreads();
  if (c < 16) sh_hx[w * 104 + 64 + c] = f2bf(X[(size_t)(base + w) * (TT * DD) + c]);
  if (tid == 0) *cnt = 0u;
  __syncthreads();

  // per-lane gate constants (interleaved layout): phys col p = 16w+m
  const float bgate = Bias[(m & 3) * 64 + 4 * w + (m >> 2)];
  const bool  isg   = (m & 3) == 2;
  const float wdc = Wd[c], bdc = Bd[0];
  const float bqv = (w < 4) ? Bq[w * 16 + m] : 0.f;        // q-GEMM col bias
  const unsigned short* afp = afrag + (kh * 16) * 512 + c * 8;
  const int gb  = c & ~3;                                  // gate-group base lane
  const int col = 4 * w + (m >> 2);                        // owned logical column
  const int ci  = quad * 16 + 4 * (w & 3) + (m >> 2);      // sh_part read col
  const int wb  = w >> 2;                                  // sh_part read tile

  float cr[4] = {0.f, 0.f, 0.f, 0.f};                      // c-state, rows quad*4+r

  // ---- initial publish: q_0 = tanh(b_q) -> ring slot 0 ----
  if (w < 4) {
    unsigned short qb = f2bf(tanh_(bqv));
    uint32_t pp = (uint32_t)qb | ((uint32_t)qb << 16);
    unsigned long long v = (unsigned long long)pp | ((unsigned long long)pp << 32);
    unsigned long long* dst =
        (unsigned long long*)(qRing + (size_t)(w * 16 + m) * (NN / 2) + (base >> 1) + 2 * quad);
    __hip_atomic_store(dst, v, __ATOMIC_RELAXED, __HIP_MEMORY_SCOPE_AGENT);
    if (!ringfull) {
      asm volatile("s_waitcnt vmcnt(0)" ::: "memory");
      if (c == 0) {
        unsigned old = atomicAdd(cnt, 1u);
        if (old == 3u)
          __hip_atomic_store(&flags[blockIdx.x * 16], 1u,
                             __ATOMIC_RELAXED, __HIP_MEMORY_SCOPE_AGENT);
      }
    }
  }

  int slotR = 0;
  for (int t = 0; t < TT; ++t) {
    const int slotW = (slotR + 1 == rdepth) ? 0 : slotR + 1;

    // ---- issue all 16 q-loads FIRST (overlap with gates + activations) ----
    const unsigned short* qslot = (const unsigned short*)(qRing + (size_t)slotR * QSLOT_U32);
    const unsigned short* qrow = qslot + (size_t)(nt * 16 + m) * NN + kh * 512 + quad * 8;
    const uint64_t qa = (uint64_t)qrow;
    u32x4 qv[16];
    if (ringfull) {
#define QL(i, offs) asm volatile("global_load_dwordx4 %0, %1, off offset:" offs " sc0 sc1" \
                                 : "=v"(qv[i]) : "v"(qa) : "memory")
      QL(0,"0");    QL(1,"64");   QL(2,"128");  QL(3,"192");
      QL(4,"256");  QL(5,"320");  QL(6,"384");  QL(7,"448");
      QL(8,"512");  QL(9,"576");  QL(10,"640"); QL(11,"704");
      QL(12,"768"); QL(13,"832"); QL(14,"896"); QL(15,"960");
#undef QL
    }

    float xnext = 0.f;                     // prefetch x_{t+1}
    if (c < 16 && t < TT - 1)
      xnext = X[(size_t)(base + w) * (TT * DD) + (t + 1) * DD + c];

    // ---- gates-GEMM (interleaved cols): D rows quad*4+r, phys col 16w+m ----
    f32x4 dg = {0.f, 0.f, 0.f, 0.f};
    {
      const unsigned short* ar = sh_hx + m * 104 + quad * 8;
      const unsigned short* br = whxT + (w * 16 + m) * 104 + quad * 8;
      #pragma unroll
      for (int ch = 0; ch < 3; ++ch)
        dg = __builtin_amdgcn_mfma_f32_16x16x32_bf16(*(const bf16x8*)(ar + ch * 32),
                                                     *(const bf16x8*)(br + ch * 32), dg, 0, 0, 0);
    }
    // per-lane activation (gate type = m&3; tanh only for gate 2)
    float act[4];
    #pragma unroll
    for (int r = 0; r < 4; ++r) {
      float pa = dg[r] + bgate;
      float sg = sigmoid_(pa);
      float th = tanh_(pa);
      act[r] = isg ? th : sg;
    }

    // ---- wait + validate (busy retry, no sleep) ----
    if (ringfull) {
      asm volatile("s_waitcnt vmcnt(0)" ::: "memory");
      __builtin_amdgcn_sched_barrier(0);
      unsigned pend = 0xFFFFu;
      #pragma unroll
      for (int ch = 0; ch < 16; ++ch)
        if (qv[ch][0] != SENT32 && qv[ch][2] != SENT32) pend &= ~(1u << ch);
      while (!__all(pend == 0)) {
#define QLD(i, offs) if (pend & (1u << i)) \
        asm volatile("global_load_dwordx4 %0, %1, off offset:" offs " sc0 sc1" \
                     : "=v"(qv[i]) : "v"(qa) : "memory")
        QLD(0,"0");    QLD(1,"64");   QLD(2,"128");  QLD(3,"192");
        QLD(4,"256");  QLD(5,"320");  QLD(6,"384");  QLD(7,"448");
        QLD(8,"512");  QLD(9,"576");  QLD(10,"640"); QLD(11,"704");
        QLD(12,"768"); QLD(13,"832"); QLD(14,"896"); QLD(15,"960");
#undef QLD
        asm volatile("s_waitcnt vmcnt(0)" ::: "memory");
        __builtin_amdgcn_sched_barrier(0);
        #pragma unroll
        for (int ch = 0; ch < 16; ++ch)
          if (pend & (1u << ch))
            if (qv[ch][0] != SENT32 && qv[ch][2] != SENT32) pend &= ~(1u << ch);
      }
    } else {
      // fallback: flag wait + fence + plain loads
      const uint32_t target = (uint32_t)(t + 1);
      const int src = 32 * kh + (c & 31);
      for (;;) {
        uint32_t f = __hip_atomic_load(&flags[src * 16],
                                       __ATOMIC_RELAXED, __HIP_MEMORY_SCOPE_AGENT);
        if (__all((int)(f >= target))) break;
        __builtin_amdgcn_s_sleep(1);
      }
      __builtin_amdgcn_fence(__ATOMIC_ACQUIRE, "agent");
      #pragma unroll
      for (int ch = 0; ch < 16; ++ch)
        qv[ch] = *(const u32x4*)(qrow + ch * 32);
    }

    // ---- phase B: Aq_t via MFMA ----
    f32x4 acc0 = {0.f,0.f,0.f,0.f}, acc1 = {0.f,0.f,0.f,0.f};
    #pragma unroll
    for (int ch = 0; ch < 16; ch += 2) {
      acc0 = __builtin_amdgcn_mfma_f32_16x16x32_bf16(
          *(const bf16x8*)(afp + ch * 512), asbf(qv[ch]), acc0, 0, 0, 0);
      acc1 = __builtin_amdgcn_mfma_f32_16x16x32_bf16(
          *(const bf16x8*)(afp + (ch + 1) * 512), asbf(qv[ch + 1]), acc1, 0, 0, 0);
    }
    sh_part[w * 65 + c] = acc0 + acc1;
    __syncthreads();                       // B3: sh_part ready

    // reduce 4 K-quarters: thread needs rows quad*4+r at its logical col
    f32x4 vsum;
    {
      const f32x4* sp = sh_part;
      f32x4 p0 = sp[(0 * 4 + wb) * 65 + ci];
      f32x4 p1 = sp[(1 * 4 + wb) * 65 + ci];
      f32x4 p2 = sp[(2 * 4 + wb) * 65 + ci];
      f32x4 p3 = sp[(3 * 4 + wb) * 65 + ci];
      vsum = (p0 + p1) + (p2 + p3);
    }

    // ---- gather gates (intra-wave) + update 4 rows (x4 redundant) ----
    #pragma unroll
    for (int r = 0; r < 4; ++r) {
      float gi = __shfl(act[r], gb + 0);
      float gf = __shfl(act[r], gb + 1);
      float gg = __shfl(act[r], gb + 2);
      float go = __shfl(act[r], gb + 3);
      cr[r] = gf * (cr[r] + vsum[r]) + gi * gg;
      float h = go * tanh_(cr[r]);
      if ((m & 3) == 0) {                  // one writer per group
        shf32[(quad * 4 + r) * 65 + col] = h;
        sh_hx[(quad * 4 + r) * 104 + col] = f2bf(h);
      }
    }
    if (c < 16) sh_hx[w * 104 + 64 + c] = f2bf(xnext);
    __syncthreads();                       // B4: h_t visible

    // ---- fused q-GEMM + publish into ring slot t+1 ----
    if (w < 4 && t < TT - 1) {
      f32x4 dq = {0.f, 0.f, 0.f, 0.f};
      const unsigned short* ar = sh_hx + m * 104 + quad * 8;
      const unsigned short* br = wqT + (w * 16 + m) * 72 + quad * 8;
      #pragma unroll
      for (int k2 = 0; k2 < 2; ++k2)
        dq = __builtin_amdgcn_mfma_f32_16x16x32_bf16(*(const bf16x8*)(ar + k2 * 32),
                                                     *(const bf16x8*)(br + k2 * 32), dq, 0, 0, 0);
      unsigned short b0 = f2bf(tanh_(dq[0] + bqv));
      unsigned short b1 = f2bf(tanh_(dq[1] + bqv));
      unsigned short b2 = f2bf(tanh_(dq[2] + bqv));
      unsigned short b3 = f2bf(tanh_(dq[3] + bqv));
      unsigned long long v =
          (unsigned long long)((uint32_t)b0 | ((uint32_t)b1 << 16)) |
          ((unsigned long long)((uint32_t)b2 | ((uint32_t)b3 << 16)) << 32);
      unsigned long long* dst =
          (unsigned long long*)(qRing + (size_t)slotW * QSLOT_U32 +
                                (size_t)(w * 16 + m) * (NN / 2) + (base >> 1) + 2 * quad);
      __hip_atomic_store(dst, v, __ATOMIC_RELAXED, __HIP_MEMORY_SCOPE_AGENT);
      if (!ringfull) {
        asm volatile("s_waitcnt vmcnt(0)" ::: "memory");
        if (c == 0) {
          unsigned old = atomicAdd(cnt, 1u);
          if (old == (unsigned)(4 * t + 7))
            __hip_atomic_store(&flags[blockIdx.x * 16], (uint32_t)(t + 2),
                               __ATOMIC_RELAXED, __HIP_MEMORY_SCOPE_AGENT);
        }
      }
    }

    // ---- output projection (f32 h from shf32; off the publish path) ----
    {
      float red = shf32[w * 65 + c] * wdc;
      #pragma unroll
      for (int off = 32; off; off >>= 1) red += __shfl_xor(red, off);
      if (c == 0) {
        union { float f; uint32_t u; } o; o.f = red + bdc;
        __hip_atomic_store((uint32_t*)&Out[(size_t)(base + w) * TT + t], o.u,
                           __ATOMIC_RELAXED, __HIP_MEMORY_SCOPE_AGENT);
      }
    }

    slotR = slotW;
  }
}

extern "C" void kernel_launch(void* const* d_in, const int* in_sizes, int n_in,
                              void* d_out, int out_size, void* d_ws, size_t ws_size,
                              hipStream_t stream) {
  const float* X    = (const float*)d_in[0];
  const float* Af   = (const float*)d_in[1];
  const float* Wih  = (const float*)d_in[2];
  const float* Whh  = (const float*)d_in[3];
  const float* Bias = (const float*)d_in[4];
  const float* Wq   = (const float*)d_in[5];
  const float* Bq   = (const float*)d_in[6];
  const float* Wd   = (const float*)d_in[7];
  const float* Bd   = (const float*)d_in[8];
  float* Out = (float*)d_out;

  char* ws = (char*)d_ws;
  uint32_t* flags = (uint32_t*)ws;                         // 128 flags, 64B apart (8 KB)
  uint32_t* qRing = (uint32_t*)(ws + 8192);                // R slots x 256 KB

  long long avail = (long long)ws_size - 8192;
  int rdepth = (int)(avail / (QSLOT_U32 * 4));
  if (rdepth > TT + 1) rdepth = TT + 1;
  if (rdepth < 2) rdepth = 2;
  int ringfull = (rdepth >= TT + 1) ? 1 : 0;

  hipFuncSetAttribute((const void*)rgcn_persist,
                      hipFuncAttributeMaxDynamicSharedMemorySize, SMEM_BYTES);
  hipMemsetAsync(ws, 0, 8192, stream);                     // zero flags (poisoned 0xAA!)
  if (ringfull)                                            // sentinel-fill the ring
    hipMemsetAsync(qRing, 0xFF, (size_t)rdepth * QSLOT_U32 * 4, stream);
  hipLaunchKernelGGL(rgcn_persist, dim3(NBLK), dim3(NTHR), SMEM_BYTES, stream,
                     X, Af, Wih, Whh, Bias, Wq, Bq, Wd, Bd, Out, qRing, flags,
                     rdepth, ringfull);
}